// Round 14
// baseline (46.341 us; speedup 1.0000x reference)
//
#include <hip/hip_runtime.h>
#include <math.h>

// Problem constants (reference is fixed-shape).
#define B_ 16
#define N_ 2048
#define D_ 128

typedef __attribute__((ext_vector_type(8))) short bf16x8;   // 8 bf16 = 4 VGPRs
typedef __attribute__((ext_vector_type(4))) float f32x4;

__device__ __forceinline__ unsigned short f2bf(float f) {
    unsigned u = __float_as_uint(f);
    u += 0x7FFFu + ((u >> 16) & 1u);
    return (unsigned short)(u >> 16);
}

__device__ __forceinline__ unsigned minkey(float f) {
    // order-preserving uint encoding of float (for atomicMin): exact, assoc.
    unsigned u = __float_as_uint(f);
    return u ^ ((unsigned)((int)u >> 31) | 0x80000000u);
}

// Fragment-order element offset within a 128x128 bf16 tile: one MFMA
// fragment-read (fixed fragment group) = 64 lanes x 16 B CONTIGUOUS (1 KB).
// Conflict-free in LDS and fully-coalesced in global by construction.
__device__ __forceinline__ int frag_off(int c, int k) {
    return ((((k >> 5) * 8 + (c >> 6) * 4 + ((c >> 4) & 3)) * 64
             + ((k >> 3) & 3) * 16 + (c & 15)) * 8) + (k & 7);
}

// ---------------------------------------------------------------------------
// K1: fp32 -> bf16 fragment-ordered tiles + fp32 squared norms + per-call
// re-init of pmk / fincnt (harness never re-poisons between replays).
// ---------------------------------------------------------------------------
__global__ __launch_bounds__(256) void prep_kernel(
        const float* __restrict__ X, unsigned short* __restrict__ Xs,
        float* __restrict__ sqn, unsigned* __restrict__ pmk,
        unsigned* __restrict__ fincnt) {
    int wv = threadIdx.x >> 6, ln = threadIdx.x & 63;
    int row0 = blockIdx.x * 16 + wv * 4;
    #pragma unroll
    for (int i = 0; i < 4; ++i) {
        int row = row0 + i;
        const float* src = X + (size_t)row * D_;
        float2 v = *(const float2*)(src + ln * 2);
        unsigned short h0 = f2bf(v.x), h1 = f2bf(v.y);
        float f0 = __uint_as_float((unsigned)h0 << 16);
        float f1 = __uint_as_float((unsigned)h1 << 16);
        float s = f0 * f0 + f1 * f1;
        #pragma unroll
        for (int o = 32; o; o >>= 1) s += __shfl_xor(s, o, 64);
        int c   = row & 127;
        int off = frag_off(c, ln * 2);     // k&7 even -> bf16 pair stays intact
        *(unsigned*)(Xs + (((size_t)(row >> 7)) << 14) + off) =
            (unsigned)h0 | ((unsigned)h1 << 16);
        if (ln == 0) { sqn[row] = s; pmk[row] = 0xFFFFFFFFu; }
    }
    if (blockIdx.x == 0 && threadIdx.x == 0) *fincnt = 0u;
}

// ---------------------------------------------------------------------------
// K2: SYMMETRIC fused Gram + min.  Round-12 recalibration: nnd at ~30 us is
// ~600 TF effective — already above the m97-structure reference for this
// shape (N=2048, K=128); the only certain large lever left is symmetry.
// 2176 WGs = 16 batches x 136 upper-triangle pairs of 128x128 tiles (53% of
// the full tile-pair work).  WG = 128 thr / 2 waves; wave owns 64 i-rows.
// 4 WGs/CU (LDS 33 KB, VGPR<=256) -> 8 waves/CU, per-CU load {8,9} WGs
// (~6% tail) — fixes R3's coarse-granularity imbalance (3T makespan).
// j-tile staged once to LDS (frag-order, conflict-free); off-diag WGs fold
// row-mins into pmk[i] AND col-mins into pmk[j] (R3's proven epilogue);
// diag WGs mask i==j by index.  XCD remap exact across rounds: 272
// consecutive ids per XCD = 2 batches.  No fences (R4 lesson).
// ---------------------------------------------------------------------------
__global__ __launch_bounds__(128, 2) void nnd_kernel(
        const unsigned short* __restrict__ Xs, const float* __restrict__ sqn,
        unsigned* __restrict__ pmk) {
    __shared__ unsigned short Xj[128 * D_];   // 32 KB j-tile (frag-order)
    __shared__ float cs[2][128];              // col-min cross-wave scratch

    // XCD-chunked remap (2176 = 8 x 272, bijective): XCD k gets ids
    // [k*272,(k+1)*272) = exactly 2 batches, valid in every dispatch round.
    int wg = (int)blockIdx.x;
    int id = (wg & 7) * 272 + (wg >> 3);
    int b  = id / 136;
    int p  = id % 136;
    int it = 0;
    while (p >= 16 - it) { p -= 16 - it; ++it; }   // upper-tri decode
    int jt = it + p;
    bool diag = (it == jt);

    int tid = threadIdx.x, wv = tid >> 6, ln = tid & 63;
    int lr = ln & 15;                 // fragment row/col lane index
    int kg = (ln >> 4) * 8;           // A/B fragment k-group offset
    int rg = (ln >> 4) * 4;           // C/D fragment row-group offset

    const unsigned short* Xb  = Xs  + (size_t)b * N_ * D_;
    const float*          sqb = sqn + b * N_;
    int ibase = it * 128 + wv * 64;   // this wave's first i-row

    // Stage j-tile: 32 KB linear copy, 2 waves x 16 x (64 lanes x 16 B).
    {
        const char* g = (const char*)(Xb + ((size_t)jt << 14)) + wv * 16384 + ln * 16;
        char*       l = (char*)Xj + wv * 16384;
        #pragma unroll
        for (int i = 0; i < 16; ++i)
            __builtin_amdgcn_global_load_lds(
                (const __attribute__((address_space(1))) unsigned int*)(g + i * 1024),
                (__attribute__((address_space(3))) unsigned int*)(l + i * 1024),
                16, 0, 0);
    }

    // A fragments: 64 rows x K=128 from the fragment-ordered global layout.
    bf16x8 Af[4][4];
    #pragma unroll
    for (int m = 0; m < 4; ++m) {
        int r = ibase + m * 16 + lr;
        const unsigned short* tp = Xb + (((size_t)(r >> 7)) << 14);
        int c = r & 127;
        #pragma unroll
        for (int ks = 0; ks < 4; ++ks)
            Af[m][ks] = *(const bf16x8*)(tp + frag_off(c, ks * 32 + kg));
    }

    // This wave's i-row norms (for the col-min side).
    float ni[4][4];
    #pragma unroll
    for (int m = 0; m < 4; ++m)
        #pragma unroll
        for (int rr = 0; rr < 4; ++rr)
            ni[m][rr] = sqb[ibase + m * 16 + rg + rr];

    float rmin[16];
    #pragma unroll
    for (int q = 0; q < 16; ++q) rmin[q] = 1e30f;
    const f32x4 zero4 = {0.f, 0.f, 0.f, 0.f};

    __syncthreads();   // staging complete (compiler drains vmcnt at barrier)

    #pragma unroll
    for (int half = 0; half < 2; ++half) {       // 64-col halves
        float nj[4];
        #pragma unroll
        for (int n = 0; n < 4; ++n)
            nj[n] = sqb[jt * 128 + half * 64 + n * 16 + lr];

        f32x4 acc[4][4];
        #pragma unroll
        for (int ks = 0; ks < 4; ++ks) {
            bf16x8 Bf[4];
            #pragma unroll
            for (int n = 0; n < 4; ++n)
                Bf[n] = *(const bf16x8*)(
                    &Xj[((ks * 8 + half * 4 + n) * 64 + ln) * 8]);
            #pragma unroll
            for (int m = 0; m < 4; ++m)
                #pragma unroll
                for (int n = 0; n < 4; ++n)
                    acc[m][n] = __builtin_amdgcn_mfma_f32_16x16x32_bf16(
                        Af[m][ks], Bf[n], ks ? acc[m][n] : zero4, 0, 0, 0);
        }

        // Epilogue.  C/D layout: col = lane&15, row = rg + reg  [m89/m91].
        if (!diag) {
            float cmin[4] = {1e30f, 1e30f, 1e30f, 1e30f};
            #pragma unroll
            for (int m = 0; m < 4; ++m)
                #pragma unroll
                for (int rr = 0; rr < 4; ++rr) {
                    float t0 = fmaf(-2.f, acc[m][0][rr], nj[0]);
                    float t1 = fmaf(-2.f, acc[m][1][rr], nj[1]);
                    float t2 = fmaf(-2.f, acc[m][2][rr], nj[2]);
                    float t3 = fmaf(-2.f, acc[m][3][rr], nj[3]);
                    rmin[m * 4 + rr] = fminf(rmin[m * 4 + rr],
                                      fminf(fminf(t0, t1), fminf(t2, t3)));
                    float nim = ni[m][rr];
                    cmin[0] = fminf(cmin[0], fmaf(-2.f, acc[m][0][rr], nim));
                    cmin[1] = fminf(cmin[1], fmaf(-2.f, acc[m][1][rr], nim));
                    cmin[2] = fminf(cmin[2], fmaf(-2.f, acc[m][2][rr], nim));
                    cmin[3] = fminf(cmin[3], fmaf(-2.f, acc[m][3][rr], nim));
                }
            #pragma unroll
            for (int n = 0; n < 4; ++n) {       // reduce 4 lane-groups/col
                float c = cmin[n];
                c = fminf(c, __shfl_xor(c, 16, 64));
                c = fminf(c, __shfl_xor(c, 32, 64));
                if (ln < 16) cs[wv][half * 64 + n * 16 + ln] = c;
            }
        } else {
            #pragma unroll
            for (int m = 0; m < 4; ++m)
                #pragma unroll
                for (int rr = 0; rr < 4; ++rr) {
                    int ir = ibase + m * 16 + rg + rr;       // global row
                    int jc = jt * 128 + half * 64 + lr;      // global col
                    float t0 = (ir == jc)      ? 1e30f
                               : fmaf(-2.f, acc[m][0][rr], nj[0]);
                    float t1 = (ir == jc + 16) ? 1e30f
                               : fmaf(-2.f, acc[m][1][rr], nj[1]);
                    float t2 = (ir == jc + 32) ? 1e30f
                               : fmaf(-2.f, acc[m][2][rr], nj[2]);
                    float t3 = (ir == jc + 48) ? 1e30f
                               : fmaf(-2.f, acc[m][3][rr], nj[3]);
                    rmin[m * 4 + rr] = fminf(rmin[m * 4 + rr],
                                      fminf(fminf(t0, t1), fminf(t2, t3)));
                }
        }
    }

    // Row-side: min across the 16 column-lanes, one atomicMin per row.
    #pragma unroll
    for (int o = 1; o < 16; o <<= 1)
        #pragma unroll
        for (int q = 0; q < 16; ++q)
            rmin[q] = fminf(rmin[q], __shfl_xor(rmin[q], o, 64));
    if (lr == 0) {
        #pragma unroll
        for (int m = 0; m < 4; ++m)
            #pragma unroll
            for (int rr = 0; rr < 4; ++rr) {
                int row = ibase + m * 16 + rg + rr;
                atomicMin(pmk + b * N_ + row, minkey(rmin[m * 4 + rr]));
            }
    }

    // Col-side: cross-wave reduce in LDS, one atomicMin per column.
    if (!diag) {
        __syncthreads();
        float c = fminf(cs[0][tid], cs[1][tid]);     // 128 thr = 128 cols
        atomicMin(pmk + b * N_ + jt * 128 + tid, minkey(c));
    }
}

// ---------------------------------------------------------------------------
// K3: decode keys -> nnd; mean / unbiased std / CV.  64 WGs x 512 thr (one
// pmk load per thread — round-8 lesson: a single-WG reader serializes 32K
// high-latency loads = +40 us).  Last WG sums the 64 slots.
// ---------------------------------------------------------------------------
__global__ __launch_bounds__(512) void finalize_kernel(
        const unsigned* __restrict__ pmk, const float* __restrict__ sqn,
        double* __restrict__ slots, unsigned* __restrict__ fincnt,
        float* __restrict__ out) {
    const int M = B_ * N_;
    int r = blockIdx.x * 512 + (int)threadIdx.x;
    unsigned key = pmk[r];
    unsigned u   = (key & 0x80000000u) ? (key ^ 0x80000000u) : ~key;
    float d2 = sqn[r] + __uint_as_float(u);
    float x32 = sqrtf(fmaxf(d2, 0.f));       // reference uses f32 sqrt too
    double x = (double)x32;
    double s1 = x, s2 = x * x;
    #pragma unroll
    for (int o = 32; o; o >>= 1) {
        s1 += __shfl_down(s1, o, 64);
        s2 += __shfl_down(s2, o, 64);
    }
    __shared__ double a1[8], a2[8];
    int wv = threadIdx.x >> 6, ln = threadIdx.x & 63;
    if (ln == 0) { a1[wv] = s1; a2[wv] = s2; }
    __syncthreads();
    if (threadIdx.x == 0) {
        double S1 = 0.0, S2 = 0.0;
        #pragma unroll
        for (int w = 0; w < 8; ++w) { S1 += a1[w]; S2 += a2[w]; }
        slots[blockIdx.x * 2]     = S1;
        slots[blockIdx.x * 2 + 1] = S2;
        __threadfence();
        unsigned old = atomicAdd(fincnt, 1u);
        if (old == 63u) {
            double T1 = 0.0, T2 = 0.0;
            for (int w = 0; w < 64; ++w) {
                T1 += __hip_atomic_load(&slots[w * 2],     __ATOMIC_RELAXED,
                                        __HIP_MEMORY_SCOPE_AGENT);
                T2 += __hip_atomic_load(&slots[w * 2 + 1], __ATOMIC_RELAXED,
                                        __HIP_MEMORY_SCOPE_AGENT);
            }
            double mean = T1 / M;
            double var  = (T2 - T1 * T1 / M) / (M - 1);
            double stdv = var > 0.0 ? sqrt(var) : 0.0;
            double cv   = (mean > 1e-8) ? stdv / fmax(mean, 1e-8) : 0.0;
            out[0] = (float)mean;
            out[1] = (float)stdv;
            out[2] = (float)cv;
        }
    }
}

extern "C" void kernel_launch(void* const* d_in, const int* in_sizes, int n_in,
                              void* d_out, int out_size, void* d_ws, size_t ws_size,
                              hipStream_t stream) {
    const float* X = (const float*)d_in[0];
    const size_t XS_BYTES = (size_t)B_ * N_ * D_ * 2;        // 8 MB
    char* ws = (char*)d_ws;
    unsigned short* Xs     = (unsigned short*)ws;
    float*          sqn    = (float*)(ws + XS_BYTES);
    unsigned*       pmk    = (unsigned*)(ws + XS_BYTES + (size_t)B_ * N_ * 4);
    double*         slots  = (double*)(ws + XS_BYTES + (size_t)B_ * N_ * 8);
    unsigned*       fincnt = (unsigned*)(ws + XS_BYTES + (size_t)B_ * N_ * 8 + 1024);
    float*          out    = (float*)d_out;

    prep_kernel<<<B_ * N_ / 16, 256, 0, stream>>>(X, Xs, sqn, pmk, fincnt);
    nnd_kernel<<<16 * 136, 128, 0, stream>>>(Xs, sqn, pmk);
    finalize_kernel<<<B_ * N_ / 512, 512, 0, stream>>>(pmk, sqn, slots, fincnt, out);
}

// Round 15
// 37.044 us; speedup vs baseline: 1.2510x; 1.2510x over previous
//
#include <hip/hip_runtime.h>
#include <math.h>

// Problem constants (reference is fixed-shape).
#define B_ 16
#define N_ 2048
#define D_ 128

typedef __attribute__((ext_vector_type(8))) short bf16x8;   // 8 bf16 = 4 VGPRs
typedef __attribute__((ext_vector_type(4))) float f32x4;

__device__ __forceinline__ unsigned short f2bf(float f) {
    unsigned u = __float_as_uint(f);
    u += 0x7FFFu + ((u >> 16) & 1u);
    return (unsigned short)(u >> 16);
}

__device__ __forceinline__ unsigned minkey(float f) {
    // order-preserving uint encoding of float (for atomicMin): exact, assoc.
    unsigned u = __float_as_uint(f);
    return u ^ ((unsigned)((int)u >> 31) | 0x80000000u);
}

// Fragment-order element offset within a 128x128 bf16 tile: one MFMA
// fragment-read (fixed fragment group) = 64 lanes x 16 B CONTIGUOUS (1 KB).
// Conflict-free in LDS and fully-coalesced in global by construction.
__device__ __forceinline__ int frag_off(int c, int k) {
    return ((((k >> 5) * 8 + (c >> 6) * 4 + ((c >> 4) & 3)) * 64
             + ((k >> 3) & 3) * 16 + (c & 15)) * 8) + (k & 7);
}

// ---------------------------------------------------------------------------
// K1: fp32 -> bf16 fragment-ordered tiles + fp32 squared norms + per-call
// re-init of pmk / fincnt (harness never re-poisons between replays).
// ---------------------------------------------------------------------------
__global__ __launch_bounds__(256) void prep_kernel(
        const float* __restrict__ X, unsigned short* __restrict__ Xs,
        float* __restrict__ sqn, unsigned* __restrict__ pmk,
        unsigned* __restrict__ fincnt) {
    int wv = threadIdx.x >> 6, ln = threadIdx.x & 63;
    int row0 = blockIdx.x * 16 + wv * 4;
    #pragma unroll
    for (int i = 0; i < 4; ++i) {
        int row = row0 + i;
        const float* src = X + (size_t)row * D_;
        float2 v = *(const float2*)(src + ln * 2);
        unsigned short h0 = f2bf(v.x), h1 = f2bf(v.y);
        float f0 = __uint_as_float((unsigned)h0 << 16);
        float f1 = __uint_as_float((unsigned)h1 << 16);
        float s = f0 * f0 + f1 * f1;
        #pragma unroll
        for (int o = 32; o; o >>= 1) s += __shfl_xor(s, o, 64);
        int c   = row & 127;
        int off = frag_off(c, ln * 2);     // k&7 even -> bf16 pair stays intact
        *(unsigned*)(Xs + (((size_t)(row >> 7)) << 14) + off) =
            (unsigned)h0 | ((unsigned)h1 << 16);
        if (ln == 0) { sqn[row] = s; pmk[row] = 0xFFFFFFFFu; }
    }
    if (blockIdx.x == 0 && threadIdx.x == 0) *fincnt = 0u;
}

// ---------------------------------------------------------------------------
// K2: fused Gram + row-min — SINGLE-BARRIER STRUCTURE.
// Round-14 lesson: symmetry regressed (work-halving only pays when the
// halved resource binds; MFMA doesn't).  Per-step cost audit says the
// ~30 us plateau across R2..R12 matches 16 x (vmcnt-drain barrier +
// staging-latency exposure), not any busy-resource floor (LDS ~4 us,
// MFMA ~2 us).  This round removes per-step syncs entirely:
//   256 WGs (exactly 1/CU, ONE round) = 16 b x 4 it(512 rows) x 4 jh(512
//   cols).  WG = 512 thr / 8 waves, wave owns 64 i-rows (proven loop).
//   ALL FOUR j-tiles (128 KB contiguous frag-order block) staged to LDS in
//   one global_load_lds burst -> ONE __syncthreads -> sync-free compute
//   phase (4 tiles x 512 MFMAs/wave; LDS port is the only shared resource).
// Staging replication drops G=8 -> G=4 (64 -> 32 MB).  XCD remap: 32
// consecutive ids per XCD = 2 batches resident per XCD L2.  No fences.
// Row-mins merge via uint-keyed atomicMin (exact, associative, determ.).
// ---------------------------------------------------------------------------
__global__ __launch_bounds__(512, 2) void nnd_kernel(
        const unsigned short* __restrict__ Xs, const float* __restrict__ sqn,
        unsigned* __restrict__ pmk) {
    __shared__ unsigned short Xj[4 * 128 * D_];   // 128 KB: 4 j-tiles

    // XCD-chunked remap (256 = 8 x 32, bijective).
    int wg  = (int)blockIdx.x;
    int id  = (wg & 7) * 32 + (wg >> 3);
    int b   = id >> 4;           // 16 ids per batch
    int sub = id & 15;
    int it  = sub >> 2;          // 512-row i-block (4 per batch)
    int jh  = sub & 3;           // 512-col j-quarter (4 tiles of 128)

    int tid = threadIdx.x, wv = tid >> 6, ln = tid & 63;
    int lr = ln & 15;                 // fragment row/col lane index
    int kg = (ln >> 4) * 8;           // A/B fragment k-group offset
    int rg = (ln >> 4) * 4;           // C/D fragment row-group offset

    const unsigned short* Xb  = Xs  + (size_t)b * N_ * D_;
    const float*          sqb = sqn + b * N_;
    int ibase = it * 512 + wv * 64;   // this wave's first i-row

    // Stage all 4 j-tiles: 128 KB contiguous linear copy, 8 waves x 16 KB.
    {
        const char* g = (const char*)(Xb + ((size_t)(jh * 4) << 14))
                        + wv * 16384 + ln * 16;
        char*       l = (char*)Xj + wv * 16384;
        #pragma unroll
        for (int i = 0; i < 16; ++i)
            __builtin_amdgcn_global_load_lds(
                (const __attribute__((address_space(1))) unsigned int*)(g + i * 1024),
                (__attribute__((address_space(3))) unsigned int*)(l + i * 1024),
                16, 0, 0);
    }

    // A fragments: 64 rows x K=128 from the fragment-ordered global layout
    // (issued during staging flight; independent of LDS).
    bf16x8 Af[4][4];
    #pragma unroll
    for (int m = 0; m < 4; ++m) {
        int r = ibase + m * 16 + lr;
        const unsigned short* tp = Xb + (((size_t)(r >> 7)) << 14);
        int c = r & 127;
        #pragma unroll
        for (int ks = 0; ks < 4; ++ks)
            Af[m][ks] = *(const bf16x8*)(tp + frag_off(c, ks * 32 + kg));
    }

    float rmin[16];
    #pragma unroll
    for (int q = 0; q < 16; ++q) rmin[q] = 1e30f;
    const f32x4 zero4 = {0.f, 0.f, 0.f, 0.f};

    __syncthreads();   // THE ONLY BARRIER: staging complete (vmcnt drained)

    #pragma unroll
    for (int t = 0; t < 4; ++t) {
        int jt = jh * 4 + t;
        const unsigned short* L = Xj + ((size_t)t << 14);
        bool dtile = (jt >> 2) == it;      // j-tile inside this i-512-range

        #pragma unroll
        for (int half = 0; half < 2; ++half) {       // 64-col halves
            float nj[4];
            #pragma unroll
            for (int n = 0; n < 4; ++n)
                nj[n] = sqb[jt * 128 + half * 64 + n * 16 + lr];

            f32x4 acc[4][4];
            #pragma unroll
            for (int ks = 0; ks < 4; ++ks) {
                bf16x8 Bf[4];
                #pragma unroll
                for (int n = 0; n < 4; ++n)
                    Bf[n] = *(const bf16x8*)(
                        &L[((ks * 8 + half * 4 + n) * 64 + ln) * 8]);
                #pragma unroll
                for (int m = 0; m < 4; ++m)
                    #pragma unroll
                    for (int n = 0; n < 4; ++n)
                        acc[m][n] = __builtin_amdgcn_mfma_f32_16x16x32_bf16(
                            Af[m][ks], Bf[n], ks ? acc[m][n] : zero4, 0, 0, 0);
            }

            // Fold min_j (n_j - 2 g).  C/D: col = lane&15, row = rg + reg.
            if (!dtile) {
                #pragma unroll
                for (int m = 0; m < 4; ++m)
                    #pragma unroll
                    for (int rr = 0; rr < 4; ++rr) {
                        float t0 = fmaf(-2.f, acc[m][0][rr], nj[0]);
                        float t1 = fmaf(-2.f, acc[m][1][rr], nj[1]);
                        float t2 = fmaf(-2.f, acc[m][2][rr], nj[2]);
                        float t3 = fmaf(-2.f, acc[m][3][rr], nj[3]);
                        rmin[m * 4 + rr] = fminf(rmin[m * 4 + rr],
                                          fminf(fminf(t0, t1), fminf(t2, t3)));
                    }
            } else {
                #pragma unroll
                for (int m = 0; m < 4; ++m)
                    #pragma unroll
                    for (int rr = 0; rr < 4; ++rr) {
                        int ir = ibase + m * 16 + rg + rr;       // global row
                        int jc = jt * 128 + half * 64 + lr;      // global col
                        float t0 = (ir == jc)      ? 1e30f
                                   : fmaf(-2.f, acc[m][0][rr], nj[0]);
                        float t1 = (ir == jc + 16) ? 1e30f
                                   : fmaf(-2.f, acc[m][1][rr], nj[1]);
                        float t2 = (ir == jc + 32) ? 1e30f
                                   : fmaf(-2.f, acc[m][2][rr], nj[2]);
                        float t3 = (ir == jc + 48) ? 1e30f
                                   : fmaf(-2.f, acc[m][3][rr], nj[3]);
                        rmin[m * 4 + rr] = fminf(rmin[m * 4 + rr],
                                          fminf(fminf(t0, t1), fminf(t2, t3)));
                    }
            }
        }
    }

    // Min across the 16 column-lanes, then one atomicMin per row.
    #pragma unroll
    for (int o = 1; o < 16; o <<= 1)
        #pragma unroll
        for (int q = 0; q < 16; ++q)
            rmin[q] = fminf(rmin[q], __shfl_xor(rmin[q], o, 64));
    if (lr == 0) {
        #pragma unroll
        for (int m = 0; m < 4; ++m)
            #pragma unroll
            for (int rr = 0; rr < 4; ++rr) {
                int row = ibase + m * 16 + rg + rr;
                atomicMin(pmk + b * N_ + row, minkey(rmin[m * 4 + rr]));
            }
    }
}

// ---------------------------------------------------------------------------
// K3: decode keys -> nnd; mean / unbiased std / CV.  64 WGs x 512 thr (one
// pmk load per thread — round-8 lesson: a single-WG reader serializes 32K
// high-latency loads = +40 us).  Last WG sums the 64 slots.
// ---------------------------------------------------------------------------
__global__ __launch_bounds__(512) void finalize_kernel(
        const unsigned* __restrict__ pmk, const float* __restrict__ sqn,
        double* __restrict__ slots, unsigned* __restrict__ fincnt,
        float* __restrict__ out) {
    const int M = B_ * N_;
    int r = blockIdx.x * 512 + (int)threadIdx.x;
    unsigned key = pmk[r];
    unsigned u   = (key & 0x80000000u) ? (key ^ 0x80000000u) : ~key;
    float d2 = sqn[r] + __uint_as_float(u);
    float x32 = sqrtf(fmaxf(d2, 0.f));       // reference uses f32 sqrt too
    double x = (double)x32;
    double s1 = x, s2 = x * x;
    #pragma unroll
    for (int o = 32; o; o >>= 1) {
        s1 += __shfl_down(s1, o, 64);
        s2 += __shfl_down(s2, o, 64);
    }
    __shared__ double a1[8], a2[8];
    int wv = threadIdx.x >> 6, ln = threadIdx.x & 63;
    if (ln == 0) { a1[wv] = s1; a2[wv] = s2; }
    __syncthreads();
    if (threadIdx.x == 0) {
        double S1 = 0.0, S2 = 0.0;
        #pragma unroll
        for (int w = 0; w < 8; ++w) { S1 += a1[w]; S2 += a2[w]; }
        slots[blockIdx.x * 2]     = S1;
        slots[blockIdx.x * 2 + 1] = S2;
        __threadfence();
        unsigned old = atomicAdd(fincnt, 1u);
        if (old == 63u) {
            double T1 = 0.0, T2 = 0.0;
            for (int w = 0; w < 64; ++w) {
                T1 += __hip_atomic_load(&slots[w * 2],     __ATOMIC_RELAXED,
                                        __HIP_MEMORY_SCOPE_AGENT);
                T2 += __hip_atomic_load(&slots[w * 2 + 1], __ATOMIC_RELAXED,
                                        __HIP_MEMORY_SCOPE_AGENT);
            }
            double mean = T1 / M;
            double var  = (T2 - T1 * T1 / M) / (M - 1);
            double stdv = var > 0.0 ? sqrt(var) : 0.0;
            double cv   = (mean > 1e-8) ? stdv / fmax(mean, 1e-8) : 0.0;
            out[0] = (float)mean;
            out[1] = (float)stdv;
            out[2] = (float)cv;
        }
    }
}

extern "C" void kernel_launch(void* const* d_in, const int* in_sizes, int n_in,
                              void* d_out, int out_size, void* d_ws, size_t ws_size,
                              hipStream_t stream) {
    const float* X = (const float*)d_in[0];
    const size_t XS_BYTES = (size_t)B_ * N_ * D_ * 2;        // 8 MB
    char* ws = (char*)d_ws;
    unsigned short* Xs     = (unsigned short*)ws;
    float*          sqn    = (float*)(ws + XS_BYTES);
    unsigned*       pmk    = (unsigned*)(ws + XS_BYTES + (size_t)B_ * N_ * 4);
    double*         slots  = (double*)(ws + XS_BYTES + (size_t)B_ * N_ * 8);
    unsigned*       fincnt = (unsigned*)(ws + XS_BYTES + (size_t)B_ * N_ * 8 + 1024);
    float*          out    = (float*)d_out;

    prep_kernel<<<B_ * N_ / 16, 256, 0, stream>>>(X, Xs, sqn, pmk, fincnt);
    nnd_kernel<<<256, 512, 0, stream>>>(Xs, sqn, pmk);
    finalize_kernel<<<B_ * N_ / 512, 512, 0, stream>>>(pmk, sqn, slots, fincnt, out);
}